// Round 12
// baseline (400.824 us; speedup 1.0000x reference)
//
#include <hip/hip_runtime.h>
#include <cstdint>
#include <cstddef>

#define B_ 8
#define N_ 2048
#define H_ 8
#define D_ 32
#define U_ 256

typedef _Float16 half8 __attribute__((ext_vector_type(8)));
typedef _Float16 half4 __attribute__((ext_vector_type(4)));
typedef float float4v __attribute__((ext_vector_type(4)));

__device__ __forceinline__ float fast_exp2(float x) {
#if __has_builtin(__builtin_amdgcn_exp2f)
  return __builtin_amdgcn_exp2f(x);
#else
  return exp2f(x);
#endif
}

// LDS-only barrier: flush this wave's LDS ops (lgkmcnt), sync execution.
// Does NOT drain vmcnt — register-destined global prefetch loads stay in
// flight across the barrier (R10: 127 -> 122 us verified).
__device__ __forceinline__ void lds_barrier() {
  asm volatile("s_waitcnt lgkmcnt(0)\n\ts_barrier" ::: "memory");
}

// ---------------------------------------------------------------------------
// K0: prep — W transpose ONLY (64 blocks, one 64x64 subtile each).
// WT fp16 [n][k]; Wq scaled by log2(e)/sqrt(32).
// ---------------------------------------------------------------------------
__global__ __launch_bounds__(256)
void k_prep(const float* __restrict__ Wq, const float* __restrict__ Wk,
            const float* __restrict__ Wv, const float* __restrict__ Wo,
            _Float16* __restrict__ WT)
{
  __shared__ __attribute__((aligned(16))) float Ts[64][68];
  const int tid = threadIdx.x;
  const int bx = blockIdx.x;
  const int wsel = bx >> 4;
  const int t    = bx & 15;
  const float* W = (wsel == 0) ? Wq : (wsel == 1) ? Wk : (wsel == 2) ? Wv : Wo;
  const float scale = (wsel == 0) ? 0.25505413f : 1.0f;
  _Float16* dstW = WT + (size_t)wsel * (U_ * U_);
  const int r = tid >> 2, cs = tid & 3;
  const int k0 = (t >> 2) * 64, n0 = (t & 3) * 64;
#pragma unroll
  for (int j = 0; j < 4; ++j)
    *(float4v*)&Ts[r][cs * 16 + j * 4] =
        *(const float4v*)(W + (size_t)(k0 + r) * U_ + n0 + cs * 16 + j * 4);
  __syncthreads();
#pragma unroll
  for (int j = 0; j < 4; ++j) {
    half4 hv;
#pragma unroll
    for (int jj = 0; jj < 4; ++jj)
      hv[jj] = (_Float16)(Ts[cs * 16 + j * 4 + jj][r] * scale);
    *(half4*)(dstW + (size_t)(n0 + r) * U_ + k0 + cs * 16 + j * 4) = hv;
  }
}

// ---------------------------------------------------------------------------
// K1: QKV projection, K-flat single-barrier (R8 verbatim).
// ---------------------------------------------------------------------------
__global__ __launch_bounds__(256)
void k_qkv3(const float* __restrict__ X, const _Float16* __restrict__ WT,
            _Float16* __restrict__ Qg, _Float16* __restrict__ Kg,
            _Float16* __restrict__ VTg)
{
  __shared__ __attribute__((aligned(16))) _Float16 Xs[64 * 264];

  const int tid  = threadIdx.x;
  const int lane = tid & 63;
  const int w    = tid >> 6;
  const int c    = lane & 15;
  const int qd   = lane >> 4;

  const int bx   = blockIdx.x;
  const int proj = bx >> 1;
  const int nh   = bx & 1;
  const int n0l  = nh * 128;
  const int m0   = blockIdx.y * 64;
  const _Float16* WTp = WT + (size_t)proj * (U_ * U_);

  half8 bf[2][8];
#pragma unroll
  for (int nt = 0; nt < 2; ++nt)
#pragma unroll
    for (int ks = 0; ks < 8; ++ks)
      bf[nt][ks] = *(const half8*)(WTp + (size_t)(n0l + w * 32 + nt * 16 + c) * U_ + ks * 32 + qd * 8);

  {
    const int row  = tid >> 2;
    const int col0 = (tid & 3) * 64;
    const float* src = X + (size_t)(m0 + row) * U_ + col0;
    _Float16* dst = &Xs[row * 264 + col0];
#pragma unroll
    for (int i = 0; i < 8; ++i) {
      float4v a  = *(const float4v*)(src + i * 8);
      float4v b2 = *(const float4v*)(src + i * 8 + 4);
      half8 hv;
      hv[0] = (_Float16)a[0];  hv[1] = (_Float16)a[1];
      hv[2] = (_Float16)a[2];  hv[3] = (_Float16)a[3];
      hv[4] = (_Float16)b2[0]; hv[5] = (_Float16)b2[1];
      hv[6] = (_Float16)b2[2]; hv[7] = (_Float16)b2[3];
      *(half8*)(dst + i * 8) = hv;
    }
  }
  __syncthreads();

  const float4v zero4 = {0.f, 0.f, 0.f, 0.f};
  float4v acc[4][2];
#pragma unroll
  for (int i = 0; i < 4; ++i)
#pragma unroll
    for (int j = 0; j < 2; ++j) acc[i][j] = zero4;

#pragma unroll
  for (int ks = 0; ks < 8; ++ks)
#pragma unroll
    for (int mf = 0; mf < 4; ++mf) {
      half8 af = *(const half8*)&Xs[(mf * 16 + c) * 264 + ks * 32 + qd * 8];
      acc[mf][0] = __builtin_amdgcn_mfma_f32_16x16x32_f16(af, bf[0][ks], acc[mf][0], 0, 0, 0);
      acc[mf][1] = __builtin_amdgcn_mfma_f32_16x16x32_f16(af, bf[1][ks], acc[mf][1], 0, 0, 0);
    }

  const int b   = m0 >> 11;
  const int nb0 = m0 & (N_ - 1);
  if (proj < 2) {
    _Float16* Og = (proj == 0) ? Qg : Kg;
#pragma unroll
    for (int mf = 0; mf < 4; ++mf)
#pragma unroll
      for (int nt = 0; nt < 2; ++nt)
#pragma unroll
        for (int r = 0; r < 4; ++r) {
          const int rowl = mf * 16 + qd * 4 + r;
          Og[(size_t)(b * N_ + nb0 + rowl) * U_ + n0l + w * 32 + nt * 16 + c] = (_Float16)acc[mf][nt][r];
        }
  } else {
    __syncthreads();
    _Float16* tr = Xs; // [128 u][72 seq]
#pragma unroll
    for (int mf = 0; mf < 4; ++mf)
#pragma unroll
      for (int nt = 0; nt < 2; ++nt)
#pragma unroll
        for (int r = 0; r < 4; ++r)
          tr[(w * 32 + nt * 16 + c) * 72 + mf * 16 + qd * 4 + r] = (_Float16)acc[mf][nt][r];
    __syncthreads();
    const int u = tid >> 1;
    const int seg = tid & 1;
    _Float16* dst = VTg + (size_t)(b * U_ + n0l + u) * N_ + nb0 + seg * 32;
#pragma unroll
    for (int i = 0; i < 4; ++i)
      *(half8*)(dst + i * 8) = *(const half8*)&tr[u * 72 + seg * 32 + i * 8];
  }
}

// ---------------------------------------------------------------------------
// K2: fused masked flash attention + output projection.
// Round 12: R10 core (lds_barrier pipeline, 122.1 us; R11's two levers
// reverted) + FOUR LDS buffers (tile t -> buf t&3): each barrier now covers
// compute of 2 tiles + store of 2 tiles -> 32 barriers instead of 64.
// This is R9's barrier-halving WITHOUT the register doubling that killed it
// (StageRegs stays 2-tile, per-thread staging unchanged). LDS 150.5 KB
// (<160), still 1 block/CU (all we ever get). Loop kt+=4, two explicit
// phases -> all buffer indices compile-time.
// ---------------------------------------------------------------------------
#define KS_H (32 * 264)   // halves per K buffer
#define VT_H (256 * 40)   // halves per V^T buffer

struct StageRegs {
  half8 k0, v0;
  int a0, a1;
};

__global__ __launch_bounds__(1024, 4)
void k_attn(const _Float16* __restrict__ Qg, const _Float16* __restrict__ Kg,
            const _Float16* __restrict__ VTg, const int* __restrict__ Adj,
            const _Float16* __restrict__ WTo, const float* __restrict__ bo,
            float* __restrict__ Out)
{
  __shared__ __attribute__((aligned(16))) _Float16 KsB[4][KS_H];   // [32 key][264] x4
  __shared__ __attribute__((aligned(16))) _Float16 VTsB[4][VT_H];  // [256 u][40] x4
  __shared__ __attribute__((aligned(8)))  unsigned int maskB[4][64];

  const int tid  = threadIdx.x;
  const int lane = tid & 63;
  const int w    = tid >> 6;   // 0..15
  const int h    = w & 7;      // head
  const int qh   = w >> 3;     // q-half (0/1), 32 rows each
  const int c    = lane & 15;
  const int qd   = lane >> 4;
  const int wg   = blockIdx.x;
  const int b    = wg & 7;     // XCD-L2 locality
  const int q0   = (wg >> 3) * 64;

  const _Float16* kptr = Kg + (size_t)(b * N_ + (tid >> 5)) * U_ + (tid & 31) * 8;
  const _Float16* vptr = VTg + (size_t)(b * U_ + (tid >> 2)) * N_ + (tid & 3) * 8;
  const int rr = lane >> 5;
  const int kk = lane & 31;
  const int* aptr = Adj + (size_t)(b * N_ + q0 + w * 4 + rr) * N_ + kk;

  // Q as B-operand frags (pre-scaled by log2(e)/sqrt(d))
  half8 qb[2];
#pragma unroll
  for (int nt = 0; nt < 2; ++nt)
    qb[nt] = *(const half8*)(Qg + (size_t)(b * N_ + q0 + qh * 32 + nt * 16 + c) * U_ + h * D_ + qd * 8);

  const float4v init4 = {-8.f, -8.f, -8.f, -8.f}; // exp2 bias, cancels in p/l
  const float4v zero4 = {0.f, 0.f, 0.f, 0.f};
  float4v acc[2][2];
#pragma unroll
  for (int i = 0; i < 2; ++i)
#pragma unroll
    for (int j = 0; j < 2; ++j) acc[i][j] = zero4;
  float lrow[2] = {0.f, 0.f};

  auto load_tile = [&](int kt) -> StageRegs {
    StageRegs r;
    r.k0 = *(const half8*)(kptr + (size_t)kt * 32 * U_);
    r.v0 = *(const half8*)(vptr + (size_t)kt * 32);
    const int* as = aptr + (size_t)kt * 32;
    r.a0 = as[0];
    r.a1 = as[2 * N_];
    return r;
  };
  auto store_tile = [&](const StageRegs& r, int buf) {
    *(half8*)&KsB[buf][(tid >> 5) * 264 + (tid & 31) * 8] = r.k0;
    *(half8*)&VTsB[buf][(tid >> 2) * 40 + (tid & 3) * 8] = r.v0;
    unsigned long long bm;
    bm = __ballot(r.a0 > 0); if (lane == 0) *(unsigned long long*)&maskB[buf][w * 4 + 0] = bm;
    bm = __ballot(r.a1 > 0); if (lane == 0) *(unsigned long long*)&maskB[buf][w * 4 + 2] = bm;
  };
  auto compute_tile = [&](int buf) {
    half8 ka0 = *(const half8*)&KsB[buf][(0 * 16 + c) * 264 + h * D_ + qd * 8];
    half8 ka1 = *(const half8*)&KsB[buf][(1 * 16 + c) * 264 + h * D_ + qd * 8];
    half4 va[2][2];
#pragma unroll
    for (int mt = 0; mt < 2; ++mt)
#pragma unroll
      for (int kc = 0; kc < 2; ++kc)
        va[mt][kc] = *(const half4*)&VTsB[buf][(h * D_ + mt * 16 + c) * 40 + kc * 16 + qd * 4];
#pragma unroll
    for (int nt = 0; nt < 2; ++nt) {
      float4v s0 = __builtin_amdgcn_mfma_f32_16x16x32_f16(ka0, qb[nt], init4, 0, 0, 0);
      float4v s1 = __builtin_amdgcn_mfma_f32_16x16x32_f16(ka1, qb[nt], init4, 0, 0, 0);
      const unsigned int mq = maskB[buf][qh * 32 + nt * 16 + c];
      const unsigned int t0 = mq >> (qd * 4);
      const unsigned int t1 = mq >> (16 + qd * 4);
      half4 pb0, pb1;
      float ls = 0.f;
#pragma unroll
      for (int r = 0; r < 4; ++r) {
        float e0 = fast_exp2(s0[r]);
        float e1 = fast_exp2(s1[r]);
        float p0 = ((t0 >> r) & 1u) ? e0 : 0.f;
        float p1 = ((t1 >> r) & 1u) ? e1 : 0.f;
        ls += p0 + p1;
        pb0[r] = (_Float16)p0;
        pb1[r] = (_Float16)p1;
      }
      lrow[nt] += ls;
      acc[0][nt] = __builtin_amdgcn_mfma_f32_16x16x16f16(va[0][0], pb0, acc[0][nt], 0, 0, 0);
      acc[0][nt] = __builtin_amdgcn_mfma_f32_16x16x16f16(va[0][1], pb1, acc[0][nt], 0, 0, 0);
      acc[1][nt] = __builtin_amdgcn_mfma_f32_16x16x16f16(va[1][0], pb0, acc[1][nt], 0, 0, 0);
      acc[1][nt] = __builtin_amdgcn_mfma_f32_16x16x16f16(va[1][1], pb1, acc[1][nt], 0, 0, 0);
    }
  };

  // ---- prologue: tiles 0,1 staged into bufs 0,1; tiles 2,3 loads in flight
  StageRegs rA = load_tile(0);
  StageRegs rB = load_tile(1);
  store_tile(rA, 0);
  store_tile(rB, 1);
  rA = load_tile(2);
  rB = load_tile(3);
  lds_barrier();

  // ---- main loop: 2 barriers per 4 tiles (was 4). Buffer = tile & 3. ----
#pragma unroll 1
  for (int kt = 0; kt < 64; kt += 4) {
    // phase A: store tiles kt+2,kt+3 -> bufs 2,3; compute bufs 0,1
    store_tile(rA, 2);
    store_tile(rB, 3);
    if (kt + 4 < 64) {
      rA = load_tile(kt + 4);
      rB = load_tile(kt + 5);
    }
    compute_tile(0);
    compute_tile(1);
    lds_barrier();
    // phase B: store tiles kt+4,kt+5 -> bufs 0,1; compute bufs 2,3
    if (kt + 4 < 64) {
      store_tile(rA, 0);
      store_tile(rB, 1);
      if (kt + 6 < 64) {
        rA = load_tile(kt + 6);
        rB = load_tile(kt + 7);
      }
    }
    compute_tile(2);
    compute_tile(3);
    lds_barrier();
  }

  // ---- epilogue 1: reduce l across qd-groups, normalize, ctx -> LDS ----
  float rinv[2];
#pragma unroll
  for (int nt = 0; nt < 2; ++nt) {
    float l = lrow[nt];
    l += __shfl_xor(l, 16, 64);
    l += __shfl_xor(l, 32, 64);
    rinv[nt] = (l > 0.f) ? 1.f / l : 0.f;
  }
  _Float16* ctxS = (_Float16*)KsB;  // reuse K bufs 0..1: [64 q][264]
#pragma unroll
  for (int mt = 0; mt < 2; ++mt)
#pragma unroll
    for (int nt = 0; nt < 2; ++nt) {
      half4 hv;
#pragma unroll
      for (int r = 0; r < 4; ++r)
        hv[r] = (_Float16)(acc[mt][nt][r] * rinv[nt]);
      *(half4*)&ctxS[(qh * 32 + nt * 16 + c) * 264 + h * D_ + mt * 16 + qd * 4] = hv;
    }
  lds_barrier();

  // ---- epilogue 2: fused output projection (wave w owns 16 n-cols, 64 rows)
  const int n0w = w * 16;
  float4v oacc[4] = {zero4, zero4, zero4, zero4};
#pragma unroll
  for (int ks = 0; ks < 8; ++ks) {
    half8 bf = *(const half8*)(WTo + (size_t)(n0w + c) * U_ + ks * 32 + qd * 8);
#pragma unroll
    for (int mt = 0; mt < 4; ++mt) {
      half8 af = *(const half8*)&ctxS[(mt * 16 + c) * 264 + ks * 32 + qd * 8];
      oacc[mt] = __builtin_amdgcn_mfma_f32_16x16x32_f16(af, bf, oacc[mt], 0, 0, 0);
    }
  }
  const float bias = bo[n0w + c];
#pragma unroll
  for (int mt = 0; mt < 4; ++mt)
#pragma unroll
    for (int r = 0; r < 4; ++r) {
      const int rowl = mt * 16 + qd * 4 + r;
      Out[(size_t)(b * N_ + q0 + rowl) * U_ + n0w + c] = oacc[mt][r] + bias;
    }
}

// ---------------------------------------------------------------------------
extern "C" void kernel_launch(void* const* d_in, const int* in_sizes, int n_in,
                              void* d_out, int out_size, void* d_ws, size_t ws_size,
                              hipStream_t stream) {
  const float* X   = (const float*)d_in[0];
  const int*   Adj = (const int*)d_in[1];
  const float* Wq  = (const float*)d_in[2];
  const float* Wk  = (const float*)d_in[3];
  const float* Wv  = (const float*)d_in[4];
  const float* Wo  = (const float*)d_in[5];
  const float* bo  = (const float*)d_in[6];
  float* Out = (float*)d_out;

  const size_t elems = (size_t)B_ * N_ * U_;   // 4,194,304 halves = 8 MB each
  const size_t wsz   = (size_t)U_ * U_;        // 65,536 halves per weight

  // Q, K, VT, WT[4] = 24.5 MB
  _Float16* Qg  = (_Float16*)d_ws;
  _Float16* Kg  = Qg + elems;
  _Float16* VTg = Kg + elems;
  _Float16* WT  = VTg + elems;
  _Float16* WTo = WT + 3 * wsz;

  k_prep<<<dim3(64), 256, 0, stream>>>(Wq, Wk, Wv, Wo, WT);
  k_qkv3<<<dim3(6, 256), 256, 0, stream>>>(X, WT, Qg, Kg, VTg);
  k_attn<<<dim3(256), 1024, 0, stream>>>(Qg, Kg, VTg, Adj, WTo, bo, Out);
}

// Round 13
// 311.871 us; speedup vs baseline: 1.2852x; 1.2852x over previous
//
#include <hip/hip_runtime.h>
#include <cstdint>
#include <cstddef>

#define B_ 8
#define N_ 2048
#define H_ 8
#define D_ 32
#define U_ 256

typedef _Float16 half8 __attribute__((ext_vector_type(8)));
typedef _Float16 half4 __attribute__((ext_vector_type(4)));
typedef float float4v __attribute__((ext_vector_type(4)));

__device__ __forceinline__ float fast_exp2(float x) {
#if __has_builtin(__builtin_amdgcn_exp2f)
  return __builtin_amdgcn_exp2f(x);
#else
  return exp2f(x);
#endif
}

// LDS-only barrier: flush this wave's LDS ops (lgkmcnt), sync execution.
// Does NOT drain vmcnt — register-destined global prefetch loads stay in
// flight across the barrier (R10: 127 -> 122 us verified).
__device__ __forceinline__ void lds_barrier() {
  asm volatile("s_waitcnt lgkmcnt(0)\n\ts_barrier" ::: "memory");
}

// ---------------------------------------------------------------------------
// K0: prep — W transpose ONLY (64 blocks, one 64x64 subtile each).
// WT fp16 [n][k]; Wq scaled by log2(e)/sqrt(32).
// ---------------------------------------------------------------------------
__global__ __launch_bounds__(256)
void k_prep(const float* __restrict__ Wq, const float* __restrict__ Wk,
            const float* __restrict__ Wv, const float* __restrict__ Wo,
            _Float16* __restrict__ WT)
{
  __shared__ __attribute__((aligned(16))) float Ts[64][68];
  const int tid = threadIdx.x;
  const int bx = blockIdx.x;
  const int wsel = bx >> 4;
  const int t    = bx & 15;
  const float* W = (wsel == 0) ? Wq : (wsel == 1) ? Wk : (wsel == 2) ? Wv : Wo;
  const float scale = (wsel == 0) ? 0.25505413f : 1.0f;
  _Float16* dstW = WT + (size_t)wsel * (U_ * U_);
  const int r = tid >> 2, cs = tid & 3;
  const int k0 = (t >> 2) * 64, n0 = (t & 3) * 64;
#pragma unroll
  for (int j = 0; j < 4; ++j)
    *(float4v*)&Ts[r][cs * 16 + j * 4] =
        *(const float4v*)(W + (size_t)(k0 + r) * U_ + n0 + cs * 16 + j * 4);
  __syncthreads();
#pragma unroll
  for (int j = 0; j < 4; ++j) {
    half4 hv;
#pragma unroll
    for (int jj = 0; jj < 4; ++jj)
      hv[jj] = (_Float16)(Ts[cs * 16 + j * 4 + jj][r] * scale);
    *(half4*)(dstW + (size_t)(n0 + r) * U_ + k0 + cs * 16 + j * 4) = hv;
  }
}

// ---------------------------------------------------------------------------
// K1: QKV projection, K-flat single-barrier (R8 verbatim).
// ---------------------------------------------------------------------------
__global__ __launch_bounds__(256)
void k_qkv3(const float* __restrict__ X, const _Float16* __restrict__ WT,
            _Float16* __restrict__ Qg, _Float16* __restrict__ Kg,
            _Float16* __restrict__ VTg)
{
  __shared__ __attribute__((aligned(16))) _Float16 Xs[64 * 264];

  const int tid  = threadIdx.x;
  const int lane = tid & 63;
  const int w    = tid >> 6;
  const int c    = lane & 15;
  const int qd   = lane >> 4;

  const int bx   = blockIdx.x;
  const int proj = bx >> 1;
  const int nh   = bx & 1;
  const int n0l  = nh * 128;
  const int m0   = blockIdx.y * 64;
  const _Float16* WTp = WT + (size_t)proj * (U_ * U_);

  half8 bf[2][8];
#pragma unroll
  for (int nt = 0; nt < 2; ++nt)
#pragma unroll
    for (int ks = 0; ks < 8; ++ks)
      bf[nt][ks] = *(const half8*)(WTp + (size_t)(n0l + w * 32 + nt * 16 + c) * U_ + ks * 32 + qd * 8);

  {
    const int row  = tid >> 2;
    const int col0 = (tid & 3) * 64;
    const float* src = X + (size_t)(m0 + row) * U_ + col0;
    _Float16* dst = &Xs[row * 264 + col0];
#pragma unroll
    for (int i = 0; i < 8; ++i) {
      float4v a  = *(const float4v*)(src + i * 8);
      float4v b2 = *(const float4v*)(src + i * 8 + 4);
      half8 hv;
      hv[0] = (_Float16)a[0];  hv[1] = (_Float16)a[1];
      hv[2] = (_Float16)a[2];  hv[3] = (_Float16)a[3];
      hv[4] = (_Float16)b2[0]; hv[5] = (_Float16)b2[1];
      hv[6] = (_Float16)b2[2]; hv[7] = (_Float16)b2[3];
      *(half8*)(dst + i * 8) = hv;
    }
  }
  __syncthreads();

  const float4v zero4 = {0.f, 0.f, 0.f, 0.f};
  float4v acc[4][2];
#pragma unroll
  for (int i = 0; i < 4; ++i)
#pragma unroll
    for (int j = 0; j < 2; ++j) acc[i][j] = zero4;

#pragma unroll
  for (int ks = 0; ks < 8; ++ks)
#pragma unroll
    for (int mf = 0; mf < 4; ++mf) {
      half8 af = *(const half8*)&Xs[(mf * 16 + c) * 264 + ks * 32 + qd * 8];
      acc[mf][0] = __builtin_amdgcn_mfma_f32_16x16x32_f16(af, bf[0][ks], acc[mf][0], 0, 0, 0);
      acc[mf][1] = __builtin_amdgcn_mfma_f32_16x16x32_f16(af, bf[1][ks], acc[mf][1], 0, 0, 0);
    }

  const int b   = m0 >> 11;
  const int nb0 = m0 & (N_ - 1);
  if (proj < 2) {
    _Float16* Og = (proj == 0) ? Qg : Kg;
#pragma unroll
    for (int mf = 0; mf < 4; ++mf)
#pragma unroll
      for (int nt = 0; nt < 2; ++nt)
#pragma unroll
        for (int r = 0; r < 4; ++r) {
          const int rowl = mf * 16 + qd * 4 + r;
          Og[(size_t)(b * N_ + nb0 + rowl) * U_ + n0l + w * 32 + nt * 16 + c] = (_Float16)acc[mf][nt][r];
        }
  } else {
    __syncthreads();
    _Float16* tr = Xs; // [128 u][72 seq]
#pragma unroll
    for (int mf = 0; mf < 4; ++mf)
#pragma unroll
      for (int nt = 0; nt < 2; ++nt)
#pragma unroll
        for (int r = 0; r < 4; ++r)
          tr[(w * 32 + nt * 16 + c) * 72 + mf * 16 + qd * 4 + r] = (_Float16)acc[mf][nt][r];
    __syncthreads();
    const int u = tid >> 1;
    const int seg = tid & 1;
    _Float16* dst = VTg + (size_t)(b * U_ + n0l + u) * N_ + nb0 + seg * 32;
#pragma unroll
    for (int i = 0; i < 4; ++i)
      *(half8*)(dst + i * 8) = *(const half8*)&tr[u * 72 + seg * 32 + i * 8];
  }
}

// ---------------------------------------------------------------------------
// K2: fused masked flash attention + output projection.
// R10 VERBATIM — the verified optimum of this session (122.1 us attn):
//   256 blocks x 1024 threads (16 waves = 8 heads x 2 q-halves), 64
//   q-rows/block, padded LDS K [32][264] + VT [256][40], adj ballots in
//   the 2-ahead register-prefetch pipeline, lds_barrier (no vmcnt drain),
//   fused Out = ctx @ Wo + bo epilogue.
// Closed experiment record: more blocks (R3), fewer rows (R6), V-from-
// global (R4), mask-hoist (R5), KVBLK=64 (R9), l-via-MFMA + VT pad (R11),
// 4-buffer barrier-halving (R12) all regress or spill. Register budget at
// 16 waves/CU (~64 VGPR) refuses any wider pipeline state.
// ---------------------------------------------------------------------------
#define KS_H (32 * 264)   // halves per K buffer
#define VT_H (256 * 40)   // halves per V^T buffer

struct StageRegs {
  half8 k0, v0;
  int a0, a1;
};

__global__ __launch_bounds__(1024, 4)
void k_attn(const _Float16* __restrict__ Qg, const _Float16* __restrict__ Kg,
            const _Float16* __restrict__ VTg, const int* __restrict__ Adj,
            const _Float16* __restrict__ WTo, const float* __restrict__ bo,
            float* __restrict__ Out)
{
  __shared__ __attribute__((aligned(16))) _Float16 KsB[2][KS_H];   // [32 key][264]
  __shared__ __attribute__((aligned(16))) _Float16 VTsB[2][VT_H];  // [256 u][40]
  __shared__ __attribute__((aligned(8)))  unsigned int maskB[2][64];

  const int tid  = threadIdx.x;
  const int lane = tid & 63;
  const int w    = tid >> 6;   // 0..15
  const int h    = w & 7;      // head
  const int qh   = w >> 3;     // q-half (0/1), 32 rows each
  const int c    = lane & 15;
  const int qd   = lane >> 4;
  const int wg   = blockIdx.x;
  const int b    = wg & 7;     // XCD-L2 locality
  const int q0   = (wg >> 3) * 64;

  const _Float16* kptr = Kg + (size_t)(b * N_ + (tid >> 5)) * U_ + (tid & 31) * 8;
  const _Float16* vptr = VTg + (size_t)(b * U_ + (tid >> 2)) * N_ + (tid & 3) * 8;
  const int rr = lane >> 5;
  const int kk = lane & 31;
  const int* aptr = Adj + (size_t)(b * N_ + q0 + w * 4 + rr) * N_ + kk;

  // Q as B-operand frags (pre-scaled by log2(e)/sqrt(d))
  half8 qb[2];
#pragma unroll
  for (int nt = 0; nt < 2; ++nt)
    qb[nt] = *(const half8*)(Qg + (size_t)(b * N_ + q0 + qh * 32 + nt * 16 + c) * U_ + h * D_ + qd * 8);

  const float4v init4 = {-8.f, -8.f, -8.f, -8.f}; // exp2 bias, cancels in p/l
  const float4v zero4 = {0.f, 0.f, 0.f, 0.f};
  float4v acc[2][2];
#pragma unroll
  for (int i = 0; i < 2; ++i)
#pragma unroll
    for (int j = 0; j < 2; ++j) acc[i][j] = zero4;
  float lrow[2] = {0.f, 0.f};

  auto load_tile = [&](int kt) -> StageRegs {
    StageRegs r;
    r.k0 = *(const half8*)(kptr + (size_t)kt * 32 * U_);
    r.v0 = *(const half8*)(vptr + (size_t)kt * 32);
    const int* as = aptr + (size_t)kt * 32;
    r.a0 = as[0];
    r.a1 = as[2 * N_];
    return r;
  };
  auto store_tile = [&](const StageRegs& r, int buf) {
    *(half8*)&KsB[buf][(tid >> 5) * 264 + (tid & 31) * 8] = r.k0;
    *(half8*)&VTsB[buf][(tid >> 2) * 40 + (tid & 3) * 8] = r.v0;
    unsigned long long bm;
    bm = __ballot(r.a0 > 0); if (lane == 0) *(unsigned long long*)&maskB[buf][w * 4 + 0] = bm;
    bm = __ballot(r.a1 > 0); if (lane == 0) *(unsigned long long*)&maskB[buf][w * 4 + 2] = bm;
  };
  auto compute_tile = [&](int buf) {
    half8 ka0 = *(const half8*)&KsB[buf][(0 * 16 + c) * 264 + h * D_ + qd * 8];
    half8 ka1 = *(const half8*)&KsB[buf][(1 * 16 + c) * 264 + h * D_ + qd * 8];
    half4 va[2][2];
#pragma unroll
    for (int mt = 0; mt < 2; ++mt)
#pragma unroll
      for (int kc = 0; kc < 2; ++kc)
        va[mt][kc] = *(const half4*)&VTsB[buf][(h * D_ + mt * 16 + c) * 40 + kc * 16 + qd * 4];
#pragma unroll
    for (int nt = 0; nt < 2; ++nt) {
      float4v s0 = __builtin_amdgcn_mfma_f32_16x16x32_f16(ka0, qb[nt], init4, 0, 0, 0);
      float4v s1 = __builtin_amdgcn_mfma_f32_16x16x32_f16(ka1, qb[nt], init4, 0, 0, 0);
      const unsigned int mq = maskB[buf][qh * 32 + nt * 16 + c];
      const unsigned int t0 = mq >> (qd * 4);
      const unsigned int t1 = mq >> (16 + qd * 4);
      half4 pb0, pb1;
      float ls = 0.f;
#pragma unroll
      for (int r = 0; r < 4; ++r) {
        float e0 = fast_exp2(s0[r]);
        float e1 = fast_exp2(s1[r]);
        float p0 = ((t0 >> r) & 1u) ? e0 : 0.f;
        float p1 = ((t1 >> r) & 1u) ? e1 : 0.f;
        ls += p0 + p1;
        pb0[r] = (_Float16)p0;
        pb1[r] = (_Float16)p1;
      }
      lrow[nt] += ls;
      acc[0][nt] = __builtin_amdgcn_mfma_f32_16x16x16f16(va[0][0], pb0, acc[0][nt], 0, 0, 0);
      acc[0][nt] = __builtin_amdgcn_mfma_f32_16x16x16f16(va[0][1], pb1, acc[0][nt], 0, 0, 0);
      acc[1][nt] = __builtin_amdgcn_mfma_f32_16x16x16f16(va[1][0], pb0, acc[1][nt], 0, 0, 0);
      acc[1][nt] = __builtin_amdgcn_mfma_f32_16x16x16f16(va[1][1], pb1, acc[1][nt], 0, 0, 0);
    }
  };

  // ---- prologue: tile 0 staged, tile 1 loads in flight ----
  StageRegs rA = load_tile(0);
  store_tile(rA, 0);
  StageRegs rB = load_tile(1);
  lds_barrier();

  // ---- pipelined main loop: loads stay in flight across barriers ----
#pragma unroll 1
  for (int kt = 0; kt < 64; kt += 2) {
    if (kt + 2 < 64) rA = load_tile(kt + 2);
    compute_tile(0);                     // tile kt
    store_tile(rB, 1);                   // tile kt+1 (loads covered by compute)
    lds_barrier();
    if (kt + 3 < 64) rB = load_tile(kt + 3);
    compute_tile(1);                     // tile kt+1
    if (kt + 2 < 64) store_tile(rA, 0);  // tile kt+2
    lds_barrier();
  }

  // ---- epilogue 1: reduce l across qd-groups, normalize, ctx -> LDS ----
  float rinv[2];
#pragma unroll
  for (int nt = 0; nt < 2; ++nt) {
    float l = lrow[nt];
    l += __shfl_xor(l, 16, 64);
    l += __shfl_xor(l, 32, 64);
    rinv[nt] = (l > 0.f) ? 1.f / l : 0.f;
  }
  _Float16* ctxS = (_Float16*)KsB;  // reuse both K buffers: [64 q][264]
#pragma unroll
  for (int mt = 0; mt < 2; ++mt)
#pragma unroll
    for (int nt = 0; nt < 2; ++nt) {
      half4 hv;
#pragma unroll
      for (int r = 0; r < 4; ++r)
        hv[r] = (_Float16)(acc[mt][nt][r] * rinv[nt]);
      *(half4*)&ctxS[(qh * 32 + nt * 16 + c) * 264 + h * D_ + mt * 16 + qd * 4] = hv;
    }
  lds_barrier();

  // ---- epilogue 2: fused output projection (wave w owns 16 n-cols, 64 rows)
  const int n0w = w * 16;
  float4v oacc[4] = {zero4, zero4, zero4, zero4};
#pragma unroll
  for (int ks = 0; ks < 8; ++ks) {
    half8 bf = *(const half8*)(WTo + (size_t)(n0w + c) * U_ + ks * 32 + qd * 8);
#pragma unroll
    for (int mt = 0; mt < 4; ++mt) {
      half8 af = *(const half8*)&ctxS[(mt * 16 + c) * 264 + ks * 32 + qd * 8];
      oacc[mt] = __builtin_amdgcn_mfma_f32_16x16x32_f16(af, bf, oacc[mt], 0, 0, 0);
    }
  }
  const float bias = bo[n0w + c];
#pragma unroll
  for (int mt = 0; mt < 4; ++mt)
#pragma unroll
    for (int r = 0; r < 4; ++r) {
      const int rowl = mt * 16 + qd * 4 + r;
      Out[(size_t)(b * N_ + q0 + rowl) * U_ + n0w + c] = oacc[mt][r] + bias;
    }
}

// ---------------------------------------------------------------------------
extern "C" void kernel_launch(void* const* d_in, const int* in_sizes, int n_in,
                              void* d_out, int out_size, void* d_ws, size_t ws_size,
                              hipStream_t stream) {
  const float* X   = (const float*)d_in[0];
  const int*   Adj = (const int*)d_in[1];
  const float* Wq  = (const float*)d_in[2];
  const float* Wk  = (const float*)d_in[3];
  const float* Wv  = (const float*)d_in[4];
  const float* Wo  = (const float*)d_in[5];
  const float* bo  = (const float*)d_in[6];
  float* Out = (float*)d_out;

  const size_t elems = (size_t)B_ * N_ * U_;   // 4,194,304 halves = 8 MB each
  const size_t wsz   = (size_t)U_ * U_;        // 65,536 halves per weight

  // Q, K, VT, WT[4] = 24.5 MB
  _Float16* Qg  = (_Float16*)d_ws;
  _Float16* Kg  = Qg + elems;
  _Float16* VTg = Kg + elems;
  _Float16* WT  = VTg + elems;
  _Float16* WTo = WT + 3 * wsz;

  k_prep<<<dim3(64), 256, 0, stream>>>(Wq, Wk, Wv, Wo, WT);
  k_qkv3<<<dim3(6, 256), 256, 0, stream>>>(X, WT, Qg, Kg, VTg);
  k_attn<<<dim3(256), 1024, 0, stream>>>(Qg, Kg, VTg, Adj, WTo, bo, Out);
}

// Round 14
// 309.554 us; speedup vs baseline: 1.2948x; 1.0075x over previous
//
#include <hip/hip_runtime.h>
#include <cstdint>
#include <cstddef>

#define B_ 8
#define N_ 2048
#define H_ 8
#define D_ 32
#define U_ 256

typedef _Float16 half8 __attribute__((ext_vector_type(8)));
typedef _Float16 half4 __attribute__((ext_vector_type(4)));
typedef float float4v __attribute__((ext_vector_type(4)));

__device__ __forceinline__ float fast_exp2(float x) {
#if __has_builtin(__builtin_amdgcn_exp2f)
  return __builtin_amdgcn_exp2f(x);
#else
  return exp2f(x);
#endif
}

// LDS-only barrier: flush this wave's LDS ops (lgkmcnt), sync execution.
// Does NOT drain vmcnt — register-destined global prefetch loads stay in
// flight across the barrier (R10: 127 -> 122 us verified).
__device__ __forceinline__ void lds_barrier() {
  asm volatile("s_waitcnt lgkmcnt(0)\n\ts_barrier" ::: "memory");
}

// ---------------------------------------------------------------------------
// K0: prep — W transpose ONLY (64 blocks, one 64x64 subtile each).
// WT fp16 [n][k]; Wq scaled by log2(e)/sqrt(32).
// ---------------------------------------------------------------------------
__global__ __launch_bounds__(256)
void k_prep(const float* __restrict__ Wq, const float* __restrict__ Wk,
            const float* __restrict__ Wv, const float* __restrict__ Wo,
            _Float16* __restrict__ WT)
{
  __shared__ __attribute__((aligned(16))) float Ts[64][68];
  const int tid = threadIdx.x;
  const int bx = blockIdx.x;
  const int wsel = bx >> 4;
  const int t    = bx & 15;
  const float* W = (wsel == 0) ? Wq : (wsel == 1) ? Wk : (wsel == 2) ? Wv : Wo;
  const float scale = (wsel == 0) ? 0.25505413f : 1.0f;
  _Float16* dstW = WT + (size_t)wsel * (U_ * U_);
  const int r = tid >> 2, cs = tid & 3;
  const int k0 = (t >> 2) * 64, n0 = (t & 3) * 64;
#pragma unroll
  for (int j = 0; j < 4; ++j)
    *(float4v*)&Ts[r][cs * 16 + j * 4] =
        *(const float4v*)(W + (size_t)(k0 + r) * U_ + n0 + cs * 16 + j * 4);
  __syncthreads();
#pragma unroll
  for (int j = 0; j < 4; ++j) {
    half4 hv;
#pragma unroll
    for (int jj = 0; jj < 4; ++jj)
      hv[jj] = (_Float16)(Ts[cs * 16 + j * 4 + jj][r] * scale);
    *(half4*)(dstW + (size_t)(n0 + r) * U_ + k0 + cs * 16 + j * 4) = hv;
  }
}

// ---------------------------------------------------------------------------
// K1: QKV projection, K-flat single-barrier. Round 14 change: Q/K epilogue
// now repacks through LDS (reusing Xs, dead after the MFMAs) and stores
// coalesced half8 rows — replacing 32 scattered 2-byte global stores per
// thread (the one component invariant across all five front-end variants
// that held ~180us; V path always did the LDS repack and was fine).
// ---------------------------------------------------------------------------
__global__ __launch_bounds__(256)
void k_qkv3(const float* __restrict__ X, const _Float16* __restrict__ WT,
            _Float16* __restrict__ Qg, _Float16* __restrict__ Kg,
            _Float16* __restrict__ VTg)
{
  __shared__ __attribute__((aligned(16))) _Float16 Xs[64 * 264];

  const int tid  = threadIdx.x;
  const int lane = tid & 63;
  const int w    = tid >> 6;
  const int c    = lane & 15;
  const int qd   = lane >> 4;

  const int bx   = blockIdx.x;
  const int proj = bx >> 1;
  const int nh   = bx & 1;
  const int n0l  = nh * 128;
  const int m0   = blockIdx.y * 64;
  const _Float16* WTp = WT + (size_t)proj * (U_ * U_);

  half8 bf[2][8];
#pragma unroll
  for (int nt = 0; nt < 2; ++nt)
#pragma unroll
    for (int ks = 0; ks < 8; ++ks)
      bf[nt][ks] = *(const half8*)(WTp + (size_t)(n0l + w * 32 + nt * 16 + c) * U_ + ks * 32 + qd * 8);

  {
    const int row  = tid >> 2;
    const int col0 = (tid & 3) * 64;
    const float* src = X + (size_t)(m0 + row) * U_ + col0;
    _Float16* dst = &Xs[row * 264 + col0];
#pragma unroll
    for (int i = 0; i < 8; ++i) {
      float4v a  = *(const float4v*)(src + i * 8);
      float4v b2 = *(const float4v*)(src + i * 8 + 4);
      half8 hv;
      hv[0] = (_Float16)a[0];  hv[1] = (_Float16)a[1];
      hv[2] = (_Float16)a[2];  hv[3] = (_Float16)a[3];
      hv[4] = (_Float16)b2[0]; hv[5] = (_Float16)b2[1];
      hv[6] = (_Float16)b2[2]; hv[7] = (_Float16)b2[3];
      *(half8*)(dst + i * 8) = hv;
    }
  }
  __syncthreads();

  const float4v zero4 = {0.f, 0.f, 0.f, 0.f};
  float4v acc[4][2];
#pragma unroll
  for (int i = 0; i < 4; ++i)
#pragma unroll
    for (int j = 0; j < 2; ++j) acc[i][j] = zero4;

#pragma unroll
  for (int ks = 0; ks < 8; ++ks)
#pragma unroll
    for (int mf = 0; mf < 4; ++mf) {
      half8 af = *(const half8*)&Xs[(mf * 16 + c) * 264 + ks * 32 + qd * 8];
      acc[mf][0] = __builtin_amdgcn_mfma_f32_16x16x32_f16(af, bf[0][ks], acc[mf][0], 0, 0, 0);
      acc[mf][1] = __builtin_amdgcn_mfma_f32_16x16x32_f16(af, bf[1][ks], acc[mf][1], 0, 0, 0);
    }

  const int b   = m0 >> 11;
  const int nb0 = m0 & (N_ - 1);
  if (proj < 2) {
    _Float16* Og = (proj == 0) ? Qg : Kg;
    __syncthreads();               // all waves done reading Xs
    _Float16* st = Xs;             // reuse: [64 rows][132] staging
#pragma unroll
    for (int mf = 0; mf < 4; ++mf)
#pragma unroll
      for (int nt = 0; nt < 2; ++nt)
#pragma unroll
        for (int r = 0; r < 4; ++r)
          st[(mf * 16 + qd * 4 + r) * 132 + w * 32 + nt * 16 + c] = (_Float16)acc[mf][nt][r];
    __syncthreads();
    const int row = tid >> 2;      // 0..63
    const int seg = tid & 3;       // 32 halves each
    _Float16* dst = Og + (size_t)(b * N_ + nb0 + row) * U_ + n0l + seg * 32;
    const _Float16* src = &st[row * 132 + seg * 32];
#pragma unroll
    for (int i = 0; i < 4; ++i)
      *(half8*)(dst + i * 8) = *(const half8*)(src + i * 8);
  } else {
    __syncthreads();
    _Float16* tr = Xs; // [128 u][72 seq]
#pragma unroll
    for (int mf = 0; mf < 4; ++mf)
#pragma unroll
      for (int nt = 0; nt < 2; ++nt)
#pragma unroll
        for (int r = 0; r < 4; ++r)
          tr[(w * 32 + nt * 16 + c) * 72 + mf * 16 + qd * 4 + r] = (_Float16)acc[mf][nt][r];
    __syncthreads();
    const int u = tid >> 1;
    const int seg = tid & 1;
    _Float16* dst = VTg + (size_t)(b * U_ + n0l + u) * N_ + nb0 + seg * 32;
#pragma unroll
    for (int i = 0; i < 4; ++i)
      *(half8*)(dst + i * 8) = *(const half8*)&tr[u * 72 + seg * 32 + i * 8];
  }
}

// ---------------------------------------------------------------------------
// K2: fused masked flash attention + output projection.
// R10/R13 VERBATIM — the verified optimum (122-127 us):
//   256 blocks x 1024 threads (16 waves = 8 heads x 2 q-halves), 64
//   q-rows/block, padded LDS K [32][264] + VT [256][40], adj ballots in
//   the 2-ahead register-prefetch pipeline, lds_barrier (no vmcnt drain),
//   fused Out = ctx @ Wo + bo epilogue.
// ---------------------------------------------------------------------------
#define KS_H (32 * 264)   // halves per K buffer
#define VT_H (256 * 40)   // halves per V^T buffer

struct StageRegs {
  half8 k0, v0;
  int a0, a1;
};

__global__ __launch_bounds__(1024, 4)
void k_attn(const _Float16* __restrict__ Qg, const _Float16* __restrict__ Kg,
            const _Float16* __restrict__ VTg, const int* __restrict__ Adj,
            const _Float16* __restrict__ WTo, const float* __restrict__ bo,
            float* __restrict__ Out)
{
  __shared__ __attribute__((aligned(16))) _Float16 KsB[2][KS_H];   // [32 key][264]
  __shared__ __attribute__((aligned(16))) _Float16 VTsB[2][VT_H];  // [256 u][40]
  __shared__ __attribute__((aligned(8)))  unsigned int maskB[2][64];

  const int tid  = threadIdx.x;
  const int lane = tid & 63;
  const int w    = tid >> 6;   // 0..15
  const int h    = w & 7;      // head
  const int qh   = w >> 3;     // q-half (0/1), 32 rows each
  const int c    = lane & 15;
  const int qd   = lane >> 4;
  const int wg   = blockIdx.x;
  const int b    = wg & 7;     // XCD-L2 locality
  const int q0   = (wg >> 3) * 64;

  const _Float16* kptr = Kg + (size_t)(b * N_ + (tid >> 5)) * U_ + (tid & 31) * 8;
  const _Float16* vptr = VTg + (size_t)(b * U_ + (tid >> 2)) * N_ + (tid & 3) * 8;
  const int rr = lane >> 5;
  const int kk = lane & 31;
  const int* aptr = Adj + (size_t)(b * N_ + q0 + w * 4 + rr) * N_ + kk;

  // Q as B-operand frags (pre-scaled by log2(e)/sqrt(d))
  half8 qb[2];
#pragma unroll
  for (int nt = 0; nt < 2; ++nt)
    qb[nt] = *(const half8*)(Qg + (size_t)(b * N_ + q0 + qh * 32 + nt * 16 + c) * U_ + h * D_ + qd * 8);

  const float4v init4 = {-8.f, -8.f, -8.f, -8.f}; // exp2 bias, cancels in p/l
  const float4v zero4 = {0.f, 0.f, 0.f, 0.f};
  float4v acc[2][2];
#pragma unroll
  for (int i = 0; i < 2; ++i)
#pragma unroll
    for (int j = 0; j < 2; ++j) acc[i][j] = zero4;
  float lrow[2] = {0.f, 0.f};

  auto load_tile = [&](int kt) -> StageRegs {
    StageRegs r;
    r.k0 = *(const half8*)(kptr + (size_t)kt * 32 * U_);
    r.v0 = *(const half8*)(vptr + (size_t)kt * 32);
    const int* as = aptr + (size_t)kt * 32;
    r.a0 = as[0];
    r.a1 = as[2 * N_];
    return r;
  };
  auto store_tile = [&](const StageRegs& r, int buf) {
    *(half8*)&KsB[buf][(tid >> 5) * 264 + (tid & 31) * 8] = r.k0;
    *(half8*)&VTsB[buf][(tid >> 2) * 40 + (tid & 3) * 8] = r.v0;
    unsigned long long bm;
    bm = __ballot(r.a0 > 0); if (lane == 0) *(unsigned long long*)&maskB[buf][w * 4 + 0] = bm;
    bm = __ballot(r.a1 > 0); if (lane == 0) *(unsigned long long*)&maskB[buf][w * 4 + 2] = bm;
  };
  auto compute_tile = [&](int buf) {
    half8 ka0 = *(const half8*)&KsB[buf][(0 * 16 + c) * 264 + h * D_ + qd * 8];
    half8 ka1 = *(const half8*)&KsB[buf][(1 * 16 + c) * 264 + h * D_ + qd * 8];
    half4 va[2][2];
#pragma unroll
    for (int mt = 0; mt < 2; ++mt)
#pragma unroll
      for (int kc = 0; kc < 2; ++kc)
        va[mt][kc] = *(const half4*)&VTsB[buf][(h * D_ + mt * 16 + c) * 40 + kc * 16 + qd * 4];
#pragma unroll
    for (int nt = 0; nt < 2; ++nt) {
      float4v s0 = __builtin_amdgcn_mfma_f32_16x16x32_f16(ka0, qb[nt], init4, 0, 0, 0);
      float4v s1 = __builtin_amdgcn_mfma_f32_16x16x32_f16(ka1, qb[nt], init4, 0, 0, 0);
      const unsigned int mq = maskB[buf][qh * 32 + nt * 16 + c];
      const unsigned int t0 = mq >> (qd * 4);
      const unsigned int t1 = mq >> (16 + qd * 4);
      half4 pb0, pb1;
      float ls = 0.f;
#pragma unroll
      for (int r = 0; r < 4; ++r) {
        float e0 = fast_exp2(s0[r]);
        float e1 = fast_exp2(s1[r]);
        float p0 = ((t0 >> r) & 1u) ? e0 : 0.f;
        float p1 = ((t1 >> r) & 1u) ? e1 : 0.f;
        ls += p0 + p1;
        pb0[r] = (_Float16)p0;
        pb1[r] = (_Float16)p1;
      }
      lrow[nt] += ls;
      acc[0][nt] = __builtin_amdgcn_mfma_f32_16x16x16f16(va[0][0], pb0, acc[0][nt], 0, 0, 0);
      acc[0][nt] = __builtin_amdgcn_mfma_f32_16x16x16f16(va[0][1], pb1, acc[0][nt], 0, 0, 0);
      acc[1][nt] = __builtin_amdgcn_mfma_f32_16x16x16f16(va[1][0], pb0, acc[1][nt], 0, 0, 0);
      acc[1][nt] = __builtin_amdgcn_mfma_f32_16x16x16f16(va[1][1], pb1, acc[1][nt], 0, 0, 0);
    }
  };

  // ---- prologue: tile 0 staged, tile 1 loads in flight ----
  StageRegs rA = load_tile(0);
  store_tile(rA, 0);
  StageRegs rB = load_tile(1);
  lds_barrier();

  // ---- pipelined main loop: loads stay in flight across barriers ----
#pragma unroll 1
  for (int kt = 0; kt < 64; kt += 2) {
    if (kt + 2 < 64) rA = load_tile(kt + 2);
    compute_tile(0);                     // tile kt
    store_tile(rB, 1);                   // tile kt+1 (loads covered by compute)
    lds_barrier();
    if (kt + 3 < 64) rB = load_tile(kt + 3);
    compute_tile(1);                     // tile kt+1
    if (kt + 2 < 64) store_tile(rA, 0);  // tile kt+2
    lds_barrier();
  }

  // ---- epilogue 1: reduce l across qd-groups, normalize, ctx -> LDS ----
  float rinv[2];
#pragma unroll
  for (int nt = 0; nt < 2; ++nt) {
    float l = lrow[nt];
    l += __shfl_xor(l, 16, 64);
    l += __shfl_xor(l, 32, 64);
    rinv[nt] = (l > 0.f) ? 1.f / l : 0.f;
  }
  _Float16* ctxS = (_Float16*)KsB;  // reuse both K buffers: [64 q][264]
#pragma unroll
  for (int mt = 0; mt < 2; ++mt)
#pragma unroll
    for (int nt = 0; nt < 2; ++nt) {
      half4 hv;
#pragma unroll
      for (int r = 0; r < 4; ++r)
        hv[r] = (_Float16)(acc[mt][nt][r] * rinv[nt]);
      *(half4*)&ctxS[(qh * 32 + nt * 16 + c) * 264 + h * D_ + mt * 16 + qd * 4] = hv;
    }
  lds_barrier();

  // ---- epilogue 2: fused output projection (wave w owns 16 n-cols, 64 rows)
  const int n0w = w * 16;
  float4v oacc[4] = {zero4, zero4, zero4, zero4};
#pragma unroll
  for (int ks = 0; ks < 8; ++ks) {
    half8 bf = *(const half8*)(WTo + (size_t)(n0w + c) * U_ + ks * 32 + qd * 8);
#pragma unroll
    for (int mt = 0; mt < 4; ++mt) {
      half8 af = *(const half8*)&ctxS[(mt * 16 + c) * 264 + ks * 32 + qd * 8];
      oacc[mt] = __builtin_amdgcn_mfma_f32_16x16x32_f16(af, bf, oacc[mt], 0, 0, 0);
    }
  }
  const float bias = bo[n0w + c];
#pragma unroll
  for (int mt = 0; mt < 4; ++mt)
#pragma unroll
    for (int r = 0; r < 4; ++r) {
      const int rowl = mt * 16 + qd * 4 + r;
      Out[(size_t)(b * N_ + q0 + rowl) * U_ + n0w + c] = oacc[mt][r] + bias;
    }
}

// ---------------------------------------------------------------------------
extern "C" void kernel_launch(void* const* d_in, const int* in_sizes, int n_in,
                              void* d_out, int out_size, void* d_ws, size_t ws_size,
                              hipStream_t stream) {
  const float* X   = (const float*)d_in[0];
  const int*   Adj = (const int*)d_in[1];
  const float* Wq  = (const float*)d_in[2];
  const float* Wk  = (const float*)d_in[3];
  const float* Wv  = (const float*)d_in[4];
  const float* Wo  = (const float*)d_in[5];
  const float* bo  = (const float*)d_in[6];
  float* Out = (float*)d_out;

  const size_t elems = (size_t)B_ * N_ * U_;   // 4,194,304 halves = 8 MB each
  const size_t wsz   = (size_t)U_ * U_;        // 65,536 halves per weight

  // Q, K, VT, WT[4] = 24.5 MB
  _Float16* Qg  = (_Float16*)d_ws;
  _Float16* Kg  = Qg + elems;
  _Float16* VTg = Kg + elems;
  _Float16* WT  = VTg + elems;
  _Float16* WTo = WT + 3 * wsz;

  k_prep<<<dim3(64), 256, 0, stream>>>(Wq, Wk, Wv, Wo, WT);
  k_qkv3<<<dim3(6, 256), 256, 0, stream>>>(X, WT, Qg, Kg, VTg);
  k_attn<<<dim3(256), 1024, 0, stream>>>(Qg, Kg, VTg, Adj, WTo, bo, Out);
}

// Round 15
// 301.725 us; speedup vs baseline: 1.3284x; 1.0259x over previous
//
#include <hip/hip_runtime.h>
#include <cstdint>
#include <cstddef>

#define B_ 8
#define N_ 2048
#define H_ 8
#define D_ 32
#define U_ 256

typedef _Float16 half8 __attribute__((ext_vector_type(8)));
typedef _Float16 half4 __attribute__((ext_vector_type(4)));
typedef float float4v __attribute__((ext_vector_type(4)));

__device__ __forceinline__ float fast_exp2(float x) {
#if __has_builtin(__builtin_amdgcn_exp2f)
  return __builtin_amdgcn_exp2f(x);
#else
  return exp2f(x);
#endif
}

// LDS-only barrier: flush this wave's LDS ops (lgkmcnt), sync execution.
// Does NOT drain vmcnt — register-destined global prefetch loads stay in
// flight across the barrier (R10: 127 -> 122 us verified).
__device__ __forceinline__ void lds_barrier() {
  asm volatile("s_waitcnt lgkmcnt(0)\n\ts_barrier" ::: "memory");
}

// ---------------------------------------------------------------------------
// Fragment-ordered weight layout (Round 15):
//   WTf[p][ idx ] with idx = ((((n>>7)*8 + ((n>>5)&3)*2 + ((n>>4)&1))*8
//                              + (k>>5)) * 64 + lane)*8 + (k&7),
//   lane = ((k>>3)&3)*16 + (n&15), value = W[k][n] (*scale for Wq).
// A wave's MFMA B-fragment load is then ONE contiguous 1-KB request instead
// of 16 scattered 64-B requests (rows at 512-B stride) — the access pattern
// shared by qkv2/qkv3/attn-epilogue that kept the projection at ~100 us.
// ---------------------------------------------------------------------------

// ---------------------------------------------------------------------------
// K0: prep — W -> fragment-ordered WTf (64 blocks, one 64x64 subtile each).
// Wq scaled by log2(e)/sqrt(32). Writes are scattered 2-B stores (fine in a
// ~10 us kernel; the payoff is coalesced reads in the hot kernels).
// ---------------------------------------------------------------------------
__global__ __launch_bounds__(256)
void k_prep(const float* __restrict__ Wq, const float* __restrict__ Wk,
            const float* __restrict__ Wv, const float* __restrict__ Wo,
            _Float16* __restrict__ WT)
{
  __shared__ __attribute__((aligned(16))) float Ts[64][68];
  const int tid = threadIdx.x;
  const int bx = blockIdx.x;
  const int wsel = bx >> 4;
  const int t    = bx & 15;
  const float* W = (wsel == 0) ? Wq : (wsel == 1) ? Wk : (wsel == 2) ? Wv : Wo;
  const float scale = (wsel == 0) ? 0.25505413f : 1.0f;
  _Float16* dstW = WT + (size_t)wsel * (U_ * U_);
  const int r = tid >> 2, cs = tid & 3;
  const int k0 = (t >> 2) * 64, n0 = (t & 3) * 64;
#pragma unroll
  for (int j = 0; j < 4; ++j)
    *(float4v*)&Ts[r][cs * 16 + j * 4] =
        *(const float4v*)(W + (size_t)(k0 + r) * U_ + n0 + cs * 16 + j * 4);
  __syncthreads();
  const int n = n0 + r;
  const int nbase = ((n >> 7) * 8 + ((n >> 5) & 3) * 2 + ((n >> 4) & 1)) * 8;
#pragma unroll
  for (int j = 0; j < 4; ++j) {
#pragma unroll
    for (int jj = 0; jj < 4; ++jj) {
      const int k = k0 + cs * 16 + j * 4 + jj;
      const int lanei = ((k >> 3) & 3) * 16 + (n & 15);
      const size_t idx = ((size_t)(nbase + (k >> 5)) * 64 + lanei) * 8 + (k & 7);
      dstW[idx] = (_Float16)(Ts[cs * 16 + j * 4 + jj][r] * scale);
    }
  }
}

// ---------------------------------------------------------------------------
// K1: QKV projection, K-flat single-barrier (R8 structure). Round 15: the
// B-fragment loads read the fragment-ordered WTf — one contiguous 1-KB
// wave-load per bf[nt][ks] instead of 16 scattered 64-B requests.
// ---------------------------------------------------------------------------
__global__ __launch_bounds__(256)
void k_qkv3(const float* __restrict__ X, const _Float16* __restrict__ WT,
            _Float16* __restrict__ Qg, _Float16* __restrict__ Kg,
            _Float16* __restrict__ VTg)
{
  __shared__ __attribute__((aligned(16))) _Float16 Xs[64 * 264];

  const int tid  = threadIdx.x;
  const int lane = tid & 63;
  const int w    = tid >> 6;
  const int c    = lane & 15;
  const int qd   = lane >> 4;

  const int bx   = blockIdx.x;
  const int proj = bx >> 1;
  const int nh   = bx & 1;
  const int n0l  = nh * 128;
  const int m0   = blockIdx.y * 64;
  const _Float16* WTf = WT + (size_t)proj * (U_ * U_);

  half8 bf[2][8];
#pragma unroll
  for (int nt = 0; nt < 2; ++nt)
#pragma unroll
    for (int ks = 0; ks < 8; ++ks)
      bf[nt][ks] = *(const half8*)(WTf +
          ((((size_t)nh * 8 + w * 2 + nt) * 8 + ks) * 64 + lane) * 8);

  {
    const int row  = tid >> 2;
    const int col0 = (tid & 3) * 64;
    const float* src = X + (size_t)(m0 + row) * U_ + col0;
    _Float16* dst = &Xs[row * 264 + col0];
#pragma unroll
    for (int i = 0; i < 8; ++i) {
      float4v a  = *(const float4v*)(src + i * 8);
      float4v b2 = *(const float4v*)(src + i * 8 + 4);
      half8 hv;
      hv[0] = (_Float16)a[0];  hv[1] = (_Float16)a[1];
      hv[2] = (_Float16)a[2];  hv[3] = (_Float16)a[3];
      hv[4] = (_Float16)b2[0]; hv[5] = (_Float16)b2[1];
      hv[6] = (_Float16)b2[2]; hv[7] = (_Float16)b2[3];
      *(half8*)(dst + i * 8) = hv;
    }
  }
  __syncthreads();

  const float4v zero4 = {0.f, 0.f, 0.f, 0.f};
  float4v acc[4][2];
#pragma unroll
  for (int i = 0; i < 4; ++i)
#pragma unroll
    for (int j = 0; j < 2; ++j) acc[i][j] = zero4;

#pragma unroll
  for (int ks = 0; ks < 8; ++ks)
#pragma unroll
    for (int mf = 0; mf < 4; ++mf) {
      half8 af = *(const half8*)&Xs[(mf * 16 + c) * 264 + ks * 32 + qd * 8];
      acc[mf][0] = __builtin_amdgcn_mfma_f32_16x16x32_f16(af, bf[0][ks], acc[mf][0], 0, 0, 0);
      acc[mf][1] = __builtin_amdgcn_mfma_f32_16x16x32_f16(af, bf[1][ks], acc[mf][1], 0, 0, 0);
    }

  const int b   = m0 >> 11;
  const int nb0 = m0 & (N_ - 1);
  if (proj < 2) {
    _Float16* Og = (proj == 0) ? Qg : Kg;
    __syncthreads();               // all waves done reading Xs
    _Float16* st = Xs;             // reuse: [64 rows][132] staging
#pragma unroll
    for (int mf = 0; mf < 4; ++mf)
#pragma unroll
      for (int nt = 0; nt < 2; ++nt)
#pragma unroll
        for (int r = 0; r < 4; ++r)
          st[(mf * 16 + qd * 4 + r) * 132 + w * 32 + nt * 16 + c] = (_Float16)acc[mf][nt][r];
    __syncthreads();
    const int row = tid >> 2;      // 0..63
    const int seg = tid & 3;       // 32 halves each
    _Float16* dst = Og + (size_t)(b * N_ + nb0 + row) * U_ + n0l + seg * 32;
    const _Float16* src = &st[row * 132 + seg * 32];
#pragma unroll
    for (int i = 0; i < 4; ++i)
      *(half8*)(dst + i * 8) = *(const half8*)(src + i * 8);
  } else {
    __syncthreads();
    _Float16* tr = Xs; // [128 u][72 seq]
#pragma unroll
    for (int mf = 0; mf < 4; ++mf)
#pragma unroll
      for (int nt = 0; nt < 2; ++nt)
#pragma unroll
        for (int r = 0; r < 4; ++r)
          tr[(w * 32 + nt * 16 + c) * 72 + mf * 16 + qd * 4 + r] = (_Float16)acc[mf][nt][r];
    __syncthreads();
    const int u = tid >> 1;
    const int seg = tid & 1;
    _Float16* dst = VTg + (size_t)(b * U_ + n0l + u) * N_ + nb0 + seg * 32;
#pragma unroll
    for (int i = 0; i < 4; ++i)
      *(half8*)(dst + i * 8) = *(const half8*)&tr[u * 72 + seg * 32 + i * 8];
  }
}

// ---------------------------------------------------------------------------
// K2: fused masked flash attention + output projection.
// R10/R13 core VERBATIM (verified 122-127 us). Round 15: the fused-output
// epilogue reads WTo in fragment order — wave w's slab (n = w*16+c) maps to
// idx = ((w*8 + ks)*64 + lane)*8, one contiguous 1-KB load per ks.
// ---------------------------------------------------------------------------
#define KS_H (32 * 264)   // halves per K buffer
#define VT_H (256 * 40)   // halves per V^T buffer

struct StageRegs {
  half8 k0, v0;
  int a0, a1;
};

__global__ __launch_bounds__(1024, 4)
void k_attn(const _Float16* __restrict__ Qg, const _Float16* __restrict__ Kg,
            const _Float16* __restrict__ VTg, const int* __restrict__ Adj,
            const _Float16* __restrict__ WTo, const float* __restrict__ bo,
            float* __restrict__ Out)
{
  __shared__ __attribute__((aligned(16))) _Float16 KsB[2][KS_H];   // [32 key][264]
  __shared__ __attribute__((aligned(16))) _Float16 VTsB[2][VT_H];  // [256 u][40]
  __shared__ __attribute__((aligned(8)))  unsigned int maskB[2][64];

  const int tid  = threadIdx.x;
  const int lane = tid & 63;
  const int w    = tid >> 6;   // 0..15
  const int h    = w & 7;      // head
  const int qh   = w >> 3;     // q-half (0/1), 32 rows each
  const int c    = lane & 15;
  const int qd   = lane >> 4;
  const int wg   = blockIdx.x;
  const int b    = wg & 7;     // XCD-L2 locality
  const int q0   = (wg >> 3) * 64;

  const _Float16* kptr = Kg + (size_t)(b * N_ + (tid >> 5)) * U_ + (tid & 31) * 8;
  const _Float16* vptr = VTg + (size_t)(b * U_ + (tid >> 2)) * N_ + (tid & 3) * 8;
  const int rr = lane >> 5;
  const int kk = lane & 31;
  const int* aptr = Adj + (size_t)(b * N_ + q0 + w * 4 + rr) * N_ + kk;

  // Q as B-operand frags (pre-scaled by log2(e)/sqrt(d))
  half8 qb[2];
#pragma unroll
  for (int nt = 0; nt < 2; ++nt)
    qb[nt] = *(const half8*)(Qg + (size_t)(b * N_ + q0 + qh * 32 + nt * 16 + c) * U_ + h * D_ + qd * 8);

  const float4v init4 = {-8.f, -8.f, -8.f, -8.f}; // exp2 bias, cancels in p/l
  const float4v zero4 = {0.f, 0.f, 0.f, 0.f};
  float4v acc[2][2];
#pragma unroll
  for (int i = 0; i < 2; ++i)
#pragma unroll
    for (int j = 0; j < 2; ++j) acc[i][j] = zero4;
  float lrow[2] = {0.f, 0.f};

  auto load_tile = [&](int kt) -> StageRegs {
    StageRegs r;
    r.k0 = *(const half8*)(kptr + (size_t)kt * 32 * U_);
    r.v0 = *(const half8*)(vptr + (size_t)kt * 32);
    const int* as = aptr + (size_t)kt * 32;
    r.a0 = as[0];
    r.a1 = as[2 * N_];
    return r;
  };
  auto store_tile = [&](const StageRegs& r, int buf) {
    *(half8*)&KsB[buf][(tid >> 5) * 264 + (tid & 31) * 8] = r.k0;
    *(half8*)&VTsB[buf][(tid >> 2) * 40 + (tid & 3) * 8] = r.v0;
    unsigned long long bm;
    bm = __ballot(r.a0 > 0); if (lane == 0) *(unsigned long long*)&maskB[buf][w * 4 + 0] = bm;
    bm = __ballot(r.a1 > 0); if (lane == 0) *(unsigned long long*)&maskB[buf][w * 4 + 2] = bm;
  };
  auto compute_tile = [&](int buf) {
    half8 ka0 = *(const half8*)&KsB[buf][(0 * 16 + c) * 264 + h * D_ + qd * 8];
    half8 ka1 = *(const half8*)&KsB[buf][(1 * 16 + c) * 264 + h * D_ + qd * 8];
    half4 va[2][2];
#pragma unroll
    for (int mt = 0; mt < 2; ++mt)
#pragma unroll
      for (int kc = 0; kc < 2; ++kc)
        va[mt][kc] = *(const half4*)&VTsB[buf][(h * D_ + mt * 16 + c) * 40 + kc * 16 + qd * 4];
#pragma unroll
    for (int nt = 0; nt < 2; ++nt) {
      float4v s0 = __builtin_amdgcn_mfma_f32_16x16x32_f16(ka0, qb[nt], init4, 0, 0, 0);
      float4v s1 = __builtin_amdgcn_mfma_f32_16x16x32_f16(ka1, qb[nt], init4, 0, 0, 0);
      const unsigned int mq = maskB[buf][qh * 32 + nt * 16 + c];
      const unsigned int t0 = mq >> (qd * 4);
      const unsigned int t1 = mq >> (16 + qd * 4);
      half4 pb0, pb1;
      float ls = 0.f;
#pragma unroll
      for (int r = 0; r < 4; ++r) {
        float e0 = fast_exp2(s0[r]);
        float e1 = fast_exp2(s1[r]);
        float p0 = ((t0 >> r) & 1u) ? e0 : 0.f;
        float p1 = ((t1 >> r) & 1u) ? e1 : 0.f;
        ls += p0 + p1;
        pb0[r] = (_Float16)p0;
        pb1[r] = (_Float16)p1;
      }
      lrow[nt] += ls;
      acc[0][nt] = __builtin_amdgcn_mfma_f32_16x16x16f16(va[0][0], pb0, acc[0][nt], 0, 0, 0);
      acc[0][nt] = __builtin_amdgcn_mfma_f32_16x16x16f16(va[0][1], pb1, acc[0][nt], 0, 0, 0);
      acc[1][nt] = __builtin_amdgcn_mfma_f32_16x16x16f16(va[1][0], pb0, acc[1][nt], 0, 0, 0);
      acc[1][nt] = __builtin_amdgcn_mfma_f32_16x16x16f16(va[1][1], pb1, acc[1][nt], 0, 0, 0);
    }
  };

  // ---- prologue: tile 0 staged, tile 1 loads in flight ----
  StageRegs rA = load_tile(0);
  store_tile(rA, 0);
  StageRegs rB = load_tile(1);
  lds_barrier();

  // ---- pipelined main loop: loads stay in flight across barriers ----
#pragma unroll 1
  for (int kt = 0; kt < 64; kt += 2) {
    if (kt + 2 < 64) rA = load_tile(kt + 2);
    compute_tile(0);                     // tile kt
    store_tile(rB, 1);                   // tile kt+1 (loads covered by compute)
    lds_barrier();
    if (kt + 3 < 64) rB = load_tile(kt + 3);
    compute_tile(1);                     // tile kt+1
    if (kt + 2 < 64) store_tile(rA, 0);  // tile kt+2
    lds_barrier();
  }

  // ---- epilogue 1: reduce l across qd-groups, normalize, ctx -> LDS ----
  float rinv[2];
#pragma unroll
  for (int nt = 0; nt < 2; ++nt) {
    float l = lrow[nt];
    l += __shfl_xor(l, 16, 64);
    l += __shfl_xor(l, 32, 64);
    rinv[nt] = (l > 0.f) ? 1.f / l : 0.f;
  }
  _Float16* ctxS = (_Float16*)KsB;  // reuse both K buffers: [64 q][264]
#pragma unroll
  for (int mt = 0; mt < 2; ++mt)
#pragma unroll
    for (int nt = 0; nt < 2; ++nt) {
      half4 hv;
#pragma unroll
      for (int r = 0; r < 4; ++r)
        hv[r] = (_Float16)(acc[mt][nt][r] * rinv[nt]);
      *(half4*)&ctxS[(qh * 32 + nt * 16 + c) * 264 + h * D_ + mt * 16 + qd * 4] = hv;
    }
  lds_barrier();

  // ---- epilogue 2: fused output projection (wave w owns 16 n-cols, 64 rows)
  const int n0w = w * 16;
  float4v oacc[4] = {zero4, zero4, zero4, zero4};
#pragma unroll
  for (int ks = 0; ks < 8; ++ks) {
    half8 bf = *(const half8*)(WTo + (((size_t)w * 8 + ks) * 64 + lane) * 8);
#pragma unroll
    for (int mt = 0; mt < 4; ++mt) {
      half8 af = *(const half8*)&ctxS[(mt * 16 + c) * 264 + ks * 32 + qd * 8];
      oacc[mt] = __builtin_amdgcn_mfma_f32_16x16x32_f16(af, bf, oacc[mt], 0, 0, 0);
    }
  }
  const float bias = bo[n0w + c];
#pragma unroll
  for (int mt = 0; mt < 4; ++mt)
#pragma unroll
    for (int r = 0; r < 4; ++r) {
      const int rowl = mt * 16 + qd * 4 + r;
      Out[(size_t)(b * N_ + q0 + rowl) * U_ + n0w + c] = oacc[mt][r] + bias;
    }
}

// ---------------------------------------------------------------------------
extern "C" void kernel_launch(void* const* d_in, const int* in_sizes, int n_in,
                              void* d_out, int out_size, void* d_ws, size_t ws_size,
                              hipStream_t stream) {
  const float* X   = (const float*)d_in[0];
  const int*   Adj = (const int*)d_in[1];
  const float* Wq  = (const float*)d_in[2];
  const float* Wk  = (const float*)d_in[3];
  const float* Wv  = (const float*)d_in[4];
  const float* Wo  = (const float*)d_in[5];
  const float* bo  = (const float*)d_in[6];
  float* Out = (float*)d_out;

  const size_t elems = (size_t)B_ * N_ * U_;   // 4,194,304 halves = 8 MB each
  const size_t wsz   = (size_t)U_ * U_;        // 65,536 halves per weight

  // Q, K, VT, WTf[4] = 24.5 MB
  _Float16* Qg  = (_Float16*)d_ws;
  _Float16* Kg  = Qg + elems;
  _Float16* VTg = Kg + elems;
  _Float16* WT  = VTg + elems;
  _Float16* WTo = WT + 3 * wsz;

  k_prep<<<dim3(64), 256, 0, stream>>>(Wq, Wk, Wv, Wo, WT);
  k_qkv3<<<dim3(6, 256), 256, 0, stream>>>(X, WT, Qg, Kg, VTg);
  k_attn<<<dim3(256), 1024, 0, stream>>>(Qg, Kg, VTg, Adj, WTo, bo, Out);
}